// Round 1
// baseline (1497.350 us; speedup 1.0000x reference)
//
#include <hip/hip_runtime.h>

#define NQ   100000
#define PP   8
#define CC   256
#define HIDN 256
#define HH   512
#define WW   512
#define DD   258
#define DPAD 260
#define TQ   16

// ---------------------------------------------------------------------------
// Prep: fold layernorm affine (g,b) into layer-1 weights/bias, zero-pad K to 260.
//   W1eff[k][j] = g[k]*W1[k][j]  (k<258), 0 otherwise
//   b1eff[j]    = b1[j] + sum_k b[k]*W1[k][j]
// ws layout (floats): [br0 W1eff 260*256][br1 W1eff 260*256][b1eff_off 256][b1eff_wgt 256]
// ---------------------------------------------------------------------------
__global__ void prep_kernel(const float* __restrict__ og, const float* __restrict__ obl,
                            const float* __restrict__ oW1, const float* __restrict__ ob1,
                            const float* __restrict__ wg, const float* __restrict__ wbl,
                            const float* __restrict__ wW1, const float* __restrict__ wb1,
                            float* __restrict__ ws) {
    const int br = blockIdx.y;
    const float* g  = br ? wg  : og;
    const float* bl = br ? wbl : obl;
    const float* W1 = br ? wW1 : oW1;
    const float* b1 = br ? wb1 : ob1;
    float* W1eff = ws + (size_t)br * DPAD * HIDN;
    float* b1eff = ws + 2 * DPAD * HIDN + br * HIDN;

    const int k = blockIdx.x;   // 0..259
    const int j = threadIdx.x;  // 0..255
    float v = 0.f;
    if (k < DD) v = g[k] * W1[k * HIDN + j];
    W1eff[k * HIDN + j] = v;

    if (k == 0) {
        float s = b1[j];
        for (int kk = 0; kk < DD; ++kk) s += bl[kk] * W1[kk * HIDN + j];
        b1eff[j] = s;
    }
}

// ---------------------------------------------------------------------------
// Fused: layernorm -> 2x 3-layer MLP -> tanh/softmax -> bilinear gather -> out
// block = 256 threads, TQ=16 queries per block
// ---------------------------------------------------------------------------
__launch_bounds__(256, 3)
__global__ void fused_kernel(const float* __restrict__ gq,    // N*C
                             const float* __restrict__ pc,    // N*2
                             const float* __restrict__ fmap,  // H*W*C
                             const float* __restrict__ ws,
                             const float* __restrict__ oW2, const float* __restrict__ ob2,
                             const float* __restrict__ oW3, const float* __restrict__ ob3,
                             const float* __restrict__ wW2, const float* __restrict__ wb2,
                             const float* __restrict__ wW3, const float* __restrict__ wb3,
                             float* __restrict__ out) {
    __shared__ __align__(16) float xs[TQ * DPAD];   // normalized x (padded K)
    __shared__ __align__(16) float hA[TQ * HIDN];   // ping
    __shared__ __align__(16) float hB[TQ * HIDN];   // pong
    __shared__ __align__(16) float raw[TQ * 24];    // [0..15]=off_raw, [16..23]=wgt_raw
    __shared__ __align__(16) float pcs[TQ * 2];     // original projection coords

    const int t  = threadIdx.x;
    const int q0 = blockIdx.x * TQ;
    const int cg = t & 63;   // column group: columns 4*cg..4*cg+3
    const int qg = t >> 6;   // query group: queries 4*qg..4*qg+3

    // ---- stage x into LDS ----
    for (int q = 0; q < TQ; ++q)
        xs[q * DPAD + t] = gq[(size_t)(q0 + q) * CC + t];
    if (t < TQ * 2) {
        float v = pc[(size_t)q0 * 2 + t];
        pcs[t] = v;
        xs[(t >> 1) * DPAD + CC + (t & 1)] = v;   // append coords
        xs[(t >> 1) * DPAD + DD + (t & 1)] = 0.f; // zero pad 258..259
    }
    __syncthreads();

    // ---- layernorm (affine folded into W1eff/b1eff) ----
    {
        const int wv = t >> 6, ln = t & 63;
        for (int qi = 0; qi < TQ; qi += 4) {
            const int q = qi + wv;
            float s = 0.f, ss = 0.f;
            for (int k = ln; k < DD; k += 64) {
                float v = xs[q * DPAD + k];
                s += v; ss += v * v;
            }
            for (int off = 32; off > 0; off >>= 1) {
                s  += __shfl_xor(s, off, 64);
                ss += __shfl_xor(ss, off, 64);
            }
            const float mu  = s * (1.f / DD);
            const float var = fmaxf(ss * (1.f / DD) - mu * mu, 0.f);
            const float rs  = rsqrtf(var + 1e-5f);
            for (int k = ln; k < DD; k += 64)
                xs[q * DPAD + k] = (xs[q * DPAD + k] - mu) * rs;
        }
    }
    __syncthreads();

    const float* b1e_base = ws + 2 * DPAD * HIDN;

    for (int br = 0; br < 2; ++br) {
        const float* W1e = ws + (size_t)br * DPAD * HIDN;
        const float* b1e = b1e_base + br * HIDN;
        const float* W2 = br ? wW2 : oW2;
        const float* b2 = br ? wb2 : ob2;
        const float* W3 = br ? wW3 : oW3;
        const float* b3 = br ? wb3 : ob3;

        // ---- layer 1: hA = relu(xs @ W1e + b1e), K=260 ----
        {
            float acc[4][4];
            const float4 bb = *(const float4*)(b1e + 4 * cg);
            #pragma unroll
            for (int qq = 0; qq < 4; ++qq) {
                acc[qq][0] = bb.x; acc[qq][1] = bb.y; acc[qq][2] = bb.z; acc[qq][3] = bb.w;
            }
            for (int k = 0; k < DPAD; k += 4) {
                const float4 w0 = *(const float4*)(W1e + (k + 0) * HIDN + 4 * cg);
                const float4 w1 = *(const float4*)(W1e + (k + 1) * HIDN + 4 * cg);
                const float4 w2 = *(const float4*)(W1e + (k + 2) * HIDN + 4 * cg);
                const float4 w3 = *(const float4*)(W1e + (k + 3) * HIDN + 4 * cg);
                #pragma unroll
                for (int qq = 0; qq < 4; ++qq) {
                    const float4 xv = *(const float4*)(xs + (qg * 4 + qq) * DPAD + k);
                    acc[qq][0] += xv.x * w0.x + xv.y * w1.x + xv.z * w2.x + xv.w * w3.x;
                    acc[qq][1] += xv.x * w0.y + xv.y * w1.y + xv.z * w2.y + xv.w * w3.y;
                    acc[qq][2] += xv.x * w0.z + xv.y * w1.z + xv.z * w2.z + xv.w * w3.z;
                    acc[qq][3] += xv.x * w0.w + xv.y * w1.w + xv.z * w2.w + xv.w * w3.w;
                }
            }
            #pragma unroll
            for (int qq = 0; qq < 4; ++qq) {
                float4 r;
                r.x = fmaxf(acc[qq][0], 0.f); r.y = fmaxf(acc[qq][1], 0.f);
                r.z = fmaxf(acc[qq][2], 0.f); r.w = fmaxf(acc[qq][3], 0.f);
                *(float4*)(hA + (qg * 4 + qq) * HIDN + 4 * cg) = r;
            }
        }
        __syncthreads();

        // ---- layer 2: hB = relu(hA @ W2 + b2), K=256 ----
        {
            float acc[4][4];
            const float4 bb = *(const float4*)(b2 + 4 * cg);
            #pragma unroll
            for (int qq = 0; qq < 4; ++qq) {
                acc[qq][0] = bb.x; acc[qq][1] = bb.y; acc[qq][2] = bb.z; acc[qq][3] = bb.w;
            }
            for (int k = 0; k < HIDN; k += 4) {
                const float4 w0 = *(const float4*)(W2 + (k + 0) * HIDN + 4 * cg);
                const float4 w1 = *(const float4*)(W2 + (k + 1) * HIDN + 4 * cg);
                const float4 w2 = *(const float4*)(W2 + (k + 2) * HIDN + 4 * cg);
                const float4 w3 = *(const float4*)(W2 + (k + 3) * HIDN + 4 * cg);
                #pragma unroll
                for (int qq = 0; qq < 4; ++qq) {
                    const float4 xv = *(const float4*)(hA + (qg * 4 + qq) * HIDN + k);
                    acc[qq][0] += xv.x * w0.x + xv.y * w1.x + xv.z * w2.x + xv.w * w3.x;
                    acc[qq][1] += xv.x * w0.y + xv.y * w1.y + xv.z * w2.y + xv.w * w3.y;
                    acc[qq][2] += xv.x * w0.z + xv.y * w1.z + xv.z * w2.z + xv.w * w3.z;
                    acc[qq][3] += xv.x * w0.w + xv.y * w1.w + xv.z * w2.w + xv.w * w3.w;
                }
            }
            #pragma unroll
            for (int qq = 0; qq < 4; ++qq) {
                float4 r;
                r.x = fmaxf(acc[qq][0], 0.f); r.y = fmaxf(acc[qq][1], 0.f);
                r.z = fmaxf(acc[qq][2], 0.f); r.w = fmaxf(acc[qq][3], 0.f);
                *(float4*)(hB + (qg * 4 + qq) * HIDN + 4 * cg) = r;
            }
        }
        __syncthreads();

        // ---- layer 3 ----
        if (br == 0) {            // 16 output cols
            const int q = t >> 4, col = t & 15;
            float s = b3[col];
            for (int k = 0; k < HIDN; ++k) s += hB[q * HIDN + k] * W3[k * 16 + col];
            raw[q * 24 + col] = s;
        } else if (t < TQ * 8) {  // 8 output cols
            const int q = t >> 3, col = t & 7;
            float s = b3[col];
            for (int k = 0; k < HIDN; ++k) s += hB[q * HIDN + k] * W3[k * 8 + col];
            raw[q * 24 + 16 + col] = s;
        }
        __syncthreads();
    }

    // ---- epilogue scalar work: tanh, softmax, bilinear indices+weights ----
    int*   sidx = (int*)hA;            // [TQ][8][4] (aliases dead hA)
    float* sw   = hA + TQ * 8 * 4;     // [TQ][8][4]
    if (t < TQ) {
        const int q = t;
        float m = -1e30f;
        #pragma unroll
        for (int p = 0; p < 8; ++p) m = fmaxf(m, raw[q * 24 + 16 + p]);
        float e[8]; float S = 0.f;
        #pragma unroll
        for (int p = 0; p < 8; ++p) { e[p] = expf(raw[q * 24 + 16 + p] - m); S += e[p]; }
        float s2 = 0.f;
        #pragma unroll
        for (int p = 0; p < 8; ++p) { e[p] /= S; s2 += e[p]; }
        const float inv = 1.f / fmaxf(s2, 1e-8f);

        const float px = pcs[q * 2 + 0], py = pcs[q * 2 + 1];
        #pragma unroll
        for (int p = 0; p < 8; ++p) {
            const float cx = px + 2.f * tanhf(raw[q * 24 + 2 * p]);
            const float cy = py + 2.f * tanhf(raw[q * 24 + 2 * p + 1]);
            const float gx = fminf(fmaxf(2.f * cx * (1.f / (WW - 1)) - 1.f, -1.1f), 1.1f);
            const float gy = fminf(fmaxf(2.f * cy * (1.f / (HH - 1)) - 1.f, -1.1f), 1.1f);
            const float ix = fminf(fmaxf((gx + 1.f) * 0.5f * (WW - 1), 0.f), (float)(WW - 1));
            const float iy = fminf(fmaxf((gy + 1.f) * 0.5f * (HH - 1), 0.f), (float)(HH - 1));
            const float x0 = floorf(ix), y0 = floorf(iy);
            const float wx = ix - x0, wy = iy - y0;
            const int x0i = (int)x0, y0i = (int)y0;
            const int x1i = min(x0i + 1, WW - 1), y1i = min(y0i + 1, HH - 1);
            const float nwp = e[p] * inv;
            const int b = (q * 8 + p) * 4;
            sidx[b + 0] = (y0i * WW + x0i) * (CC / 4);
            sidx[b + 1] = (y0i * WW + x1i) * (CC / 4);
            sidx[b + 2] = (y1i * WW + x0i) * (CC / 4);
            sidx[b + 3] = (y1i * WW + x1i) * (CC / 4);
            sw[b + 0] = (1.f - wx) * (1.f - wy) * nwp;
            sw[b + 1] = wx * (1.f - wy) * nwp;
            sw[b + 2] = (1.f - wx) * wy * nwp;
            sw[b + 3] = wx * wy * nwp;
        }
    }
    __syncthreads();

    // ---- gather + weighted sum: thread = (4 channels) x (4 queries) ----
    const float4* fm4 = (const float4*)fmap;
    float4* out4 = (float4*)out;
    #pragma unroll
    for (int qq = 0; qq < 4; ++qq) {
        const int q = qg * 4 + qq;
        float4 acc; acc.x = acc.y = acc.z = acc.w = 0.f;
        for (int p = 0; p < 8; ++p) {
            const int b = (q * 8 + p) * 4;
            const int i00 = sidx[b + 0] + cg;
            const int i01 = sidx[b + 1] + cg;
            const int i10 = sidx[b + 2] + cg;
            const int i11 = sidx[b + 3] + cg;
            const float a00 = sw[b + 0], a01 = sw[b + 1], a10 = sw[b + 2], a11 = sw[b + 3];
            const float4 v00 = fm4[i00], v01 = fm4[i01], v10 = fm4[i10], v11 = fm4[i11];
            acc.x += a00 * v00.x + a01 * v01.x + a10 * v10.x + a11 * v11.x;
            acc.y += a00 * v00.y + a01 * v01.y + a10 * v10.y + a11 * v11.y;
            acc.z += a00 * v00.z + a01 * v01.z + a10 * v10.z + a11 * v11.z;
            acc.w += a00 * v00.w + a01 * v01.w + a10 * v10.w + a11 * v11.w;
        }
        out4[(size_t)(q0 + q) * (CC / 4) + cg] = acc;
    }
}

extern "C" void kernel_launch(void* const* d_in, const int* in_sizes, int n_in,
                              void* d_out, int out_size, void* d_ws, size_t ws_size,
                              hipStream_t stream) {
    const float* gq   = (const float*)d_in[0];
    const float* pc   = (const float*)d_in[1];
    const float* fmap = (const float*)d_in[2];
    const float* og   = (const float*)d_in[3];
    const float* obl  = (const float*)d_in[4];
    const float* oW1  = (const float*)d_in[5];
    const float* ob1  = (const float*)d_in[6];
    const float* oW2  = (const float*)d_in[7];
    const float* ob2  = (const float*)d_in[8];
    const float* oW3  = (const float*)d_in[9];
    const float* ob3  = (const float*)d_in[10];
    const float* wg   = (const float*)d_in[11];
    const float* wbl  = (const float*)d_in[12];
    const float* wW1  = (const float*)d_in[13];
    const float* wb1  = (const float*)d_in[14];
    const float* wW2  = (const float*)d_in[15];
    const float* wb2  = (const float*)d_in[16];
    const float* wW3  = (const float*)d_in[17];
    const float* wb3  = (const float*)d_in[18];
    float* ws  = (float*)d_ws;
    float* out = (float*)d_out;

    dim3 pg(DPAD, 2);
    prep_kernel<<<pg, 256, 0, stream>>>(og, obl, oW1, ob1, wg, wbl, wW1, wb1, ws);
    fused_kernel<<<NQ / TQ, 256, 0, stream>>>(gq, pc, fmap, ws,
                                              oW2, ob2, oW3, ob3,
                                              wW2, wb2, wW3, wb3, out);
}

// Round 2
// 1461.048 us; speedup vs baseline: 1.0248x; 1.0248x over previous
//
#include <hip/hip_runtime.h>

#define NQ   100000
#define PP   8
#define CC   256
#define HIDN 256
#define HH   512
#define WW   512
#define DD   258
#define KK1  288      // layer-1 K padded to 9*32
#define KK2  256
#define TQ   16
#define XS_STRIDE 296 // bf16 elems per row (2-way-conflict-free for b128 frag reads)
#define HA_STRIDE 264
#define HB_STRIDE 264

typedef __attribute__((ext_vector_type(8))) __bf16 bf16x8;
typedef __attribute__((ext_vector_type(4))) float  f32x4;

__device__ __forceinline__ unsigned short f2bf_hi(float v, float* rem) {
    __bf16 h = (__bf16)v;
    *rem = v - (float)h;
    return __builtin_bit_cast(unsigned short, h);
}
__device__ __forceinline__ unsigned short f2bf(float v) {
    __bf16 h = (__bf16)v;
    return __builtin_bit_cast(unsigned short, h);
}

// ---------------- ws layout (bytes) ----------------
// W1TH: [br][n=256][k=288] bf16   @ 0        (294912)
// W1TL:                           @ 294912   (294912)
// W2TH: [br][n=256][k=256] bf16   @ 589824   (262144)
// W2TL:                           @ 851968   (262144)
// W3T : [24][256] f32 (16 off cols, 8 wgt)   @ 1114112 (24576)
// B1E : [br][256] f32             @ 1138688  (2048)
#define WS_W1TH 0
#define WS_W1TL 294912
#define WS_W2TH 589824
#define WS_W2TL 851968
#define WS_W3T  1114112
#define WS_B1E  1138688

// ---------------------------------------------------------------------------
// prep: fold LN affine into W1, transpose + zero-pad + bf16 hi/lo split
// ---------------------------------------------------------------------------
__global__ void prep_w1(const float* __restrict__ og, const float* __restrict__ obl,
                        const float* __restrict__ oW1, const float* __restrict__ ob1,
                        const float* __restrict__ wg, const float* __restrict__ wbl,
                        const float* __restrict__ wW1, const float* __restrict__ wb1,
                        unsigned short* __restrict__ w1th, unsigned short* __restrict__ w1tl,
                        float* __restrict__ b1e) {
    const int br = blockIdx.y, k = blockIdx.x, n = threadIdx.x;
    const float* g  = br ? wg  : og;
    const float* bl = br ? wbl : obl;
    const float* W1 = br ? wW1 : oW1;
    const float* b1 = br ? wb1 : ob1;
    float v = (k < DD) ? g[k] * W1[k * HIDN + n] : 0.f;
    float rem; unsigned short hi = f2bf_hi(v, &rem);
    size_t o = (size_t)br * 256 * KK1 + (size_t)n * KK1 + k;
    w1th[o] = hi; w1tl[o] = f2bf(rem);
    if (k == 0) {
        float s = b1[n];
        for (int kk = 0; kk < DD; ++kk) s += bl[kk] * W1[kk * HIDN + n];
        b1e[br * 256 + n] = s;
    }
}

__global__ void prep_w2(const float* __restrict__ oW2, const float* __restrict__ wW2,
                        unsigned short* __restrict__ w2th, unsigned short* __restrict__ w2tl) {
    const int br = blockIdx.y, k = blockIdx.x, n = threadIdx.x;
    const float* W2 = br ? wW2 : oW2;
    float v = W2[k * HIDN + n];
    float rem; unsigned short hi = f2bf_hi(v, &rem);
    size_t o = (size_t)br * 256 * KK2 + (size_t)n * KK2 + k;
    w2th[o] = hi; w2tl[o] = f2bf(rem);
}

__global__ void prep_w3(const float* __restrict__ oW3, const float* __restrict__ wW3,
                        float* __restrict__ w3t) {
    const int br = blockIdx.x, t = threadIdx.x;
    if (br == 0) {
        const int c = t & 15, kb = t >> 4;
        for (int i = 0; i < 16; ++i) { int k = kb * 16 + i; w3t[c * 256 + k] = oW3[k * 16 + c]; }
    } else {
        const int c = t & 7, kb = t >> 3;
        for (int i = 0; i < 8; ++i)  { int k = kb * 8 + i;  w3t[(16 + c) * 256 + k] = wW3[k * 8 + c]; }
    }
}

// ---------------------------------------------------------------------------
// fused: LN -> (MFMA split-bf16 L1,L2 + fp32 L3) x2 -> softmax/tanh -> gather
// ---------------------------------------------------------------------------
__launch_bounds__(256, 3)
__global__ void fused_kernel(const float* __restrict__ gq, const float* __restrict__ pc,
                             const float* __restrict__ fmap,
                             const unsigned short* __restrict__ w1th, const unsigned short* __restrict__ w1tl,
                             const unsigned short* __restrict__ w2th, const unsigned short* __restrict__ w2tl,
                             const float* __restrict__ w3t, const float* __restrict__ b1e,
                             const float* __restrict__ ob2, const float* __restrict__ ob3,
                             const float* __restrict__ wb2, const float* __restrict__ wb3,
                             float* __restrict__ out) {
    __shared__ __align__(16) unsigned short xsh[TQ * XS_STRIDE];
    __shared__ __align__(16) unsigned short xsl[TQ * XS_STRIDE];
    __shared__ __align__(16) unsigned short hah[TQ * HA_STRIDE];
    __shared__ __align__(16) unsigned short hal[TQ * HA_STRIDE];
    __shared__ __align__(16) float hb[TQ * HB_STRIDE];
    __shared__ __align__(16) float raw[TQ * 24];
    __shared__ __align__(16) float pcs[TQ * 2];

    const int t    = threadIdx.x;
    const int q0   = blockIdx.x * TQ;
    const int lane = t & 63;
    const int wv   = t >> 6;
    const int quad = lane >> 4;
    const int l15  = lane & 15;

    // ---- zero xs pad regions; stage x (f32) into hb; coords ----
    for (int i = t; i < TQ * XS_STRIDE / 2; i += 256) {
        ((unsigned int*)xsh)[i] = 0u; ((unsigned int*)xsl)[i] = 0u;
    }
    for (int q = 0; q < TQ; ++q)
        hb[q * HB_STRIDE + t] = gq[(size_t)(q0 + q) * CC + t];
    if (t < TQ * 2) {
        float v = pc[(size_t)q0 * 2 + t];
        pcs[t] = v;
        hb[(t >> 1) * HB_STRIDE + CC + (t & 1)] = v;
    }
    __syncthreads();

    // ---- layernorm -> xs hi/lo (affine folded into W1/b1eff) ----
    for (int qi = 0; qi < TQ; qi += 4) {
        const int q = qi + wv;
        float s = 0.f, ss = 0.f;
        for (int k = lane; k < DD; k += 64) {
            float v = hb[q * HB_STRIDE + k]; s += v; ss += v * v;
        }
        for (int off = 32; off > 0; off >>= 1) {
            s += __shfl_xor(s, off, 64); ss += __shfl_xor(ss, off, 64);
        }
        const float mu = s * (1.f / DD);
        const float var = fmaxf(ss * (1.f / DD) - mu * mu, 0.f);
        const float rs = rsqrtf(var + 1e-5f);
        for (int k = lane; k < DD; k += 64) {
            float v = (hb[q * HB_STRIDE + k] - mu) * rs;
            float rem; xsh[q * XS_STRIDE + k] = f2bf_hi(v, &rem);
            xsl[q * XS_STRIDE + k] = f2bf(rem);
        }
    }
    __syncthreads();

    for (int br = 0; br < 2; ++br) {
        // ---- layer 1: hA = relu(x @ W1eff + b1eff), MFMA 16x16x32 split-bf16 ----
        {
            f32x4 acc[4];
            #pragma unroll
            for (int nt = 0; nt < 4; ++nt) {
                float b = b1e[br * 256 + wv * 64 + nt * 16 + l15];
                acc[nt] = (f32x4){b, b, b, b};
            }
            const unsigned short* Wh = w1th + (size_t)br * 256 * KK1;
            const unsigned short* Wl = w1tl + (size_t)br * 256 * KK1;
            const unsigned short* axh = xsh + l15 * XS_STRIDE + quad * 8;
            const unsigned short* axl = xsl + l15 * XS_STRIDE + quad * 8;
            for (int k0 = 0; k0 < KK1; k0 += 32) {
                const bf16x8 ah = *(const bf16x8*)(axh + k0);
                const bf16x8 al = *(const bf16x8*)(axl + k0);
                #pragma unroll
                for (int nt = 0; nt < 4; ++nt) {
                    const size_t n = wv * 64 + nt * 16 + l15;
                    const bf16x8 bh = *(const bf16x8*)(Wh + n * KK1 + k0 + quad * 8);
                    const bf16x8 bl = *(const bf16x8*)(Wl + n * KK1 + k0 + quad * 8);
                    acc[nt] = __builtin_amdgcn_mfma_f32_16x16x32_bf16(ah, bh, acc[nt], 0, 0, 0);
                    acc[nt] = __builtin_amdgcn_mfma_f32_16x16x32_bf16(ah, bl, acc[nt], 0, 0, 0);
                    acc[nt] = __builtin_amdgcn_mfma_f32_16x16x32_bf16(al, bh, acc[nt], 0, 0, 0);
                }
            }
            #pragma unroll
            for (int nt = 0; nt < 4; ++nt) {
                const int n = wv * 64 + nt * 16 + l15;
                #pragma unroll
                for (int r = 0; r < 4; ++r) {
                    const int m = quad * 4 + r;
                    float v = fmaxf(acc[nt][r], 0.f);
                    float rem; hah[m * HA_STRIDE + n] = f2bf_hi(v, &rem);
                    hal[m * HA_STRIDE + n] = f2bf(rem);
                }
            }
        }
        __syncthreads();

        // ---- layer 2: hb = relu(hA @ W2 + b2), MFMA split-bf16 ----
        {
            const float* b2 = br ? wb2 : ob2;
            f32x4 acc[4];
            #pragma unroll
            for (int nt = 0; nt < 4; ++nt) {
                float b = b2[wv * 64 + nt * 16 + l15];
                acc[nt] = (f32x4){b, b, b, b};
            }
            const unsigned short* Wh = w2th + (size_t)br * 256 * KK2;
            const unsigned short* Wl = w2tl + (size_t)br * 256 * KK2;
            const unsigned short* axh = hah + l15 * HA_STRIDE + quad * 8;
            const unsigned short* axl = hal + l15 * HA_STRIDE + quad * 8;
            for (int k0 = 0; k0 < KK2; k0 += 32) {
                const bf16x8 ah = *(const bf16x8*)(axh + k0);
                const bf16x8 al = *(const bf16x8*)(axl + k0);
                #pragma unroll
                for (int nt = 0; nt < 4; ++nt) {
                    const size_t n = wv * 64 + nt * 16 + l15;
                    const bf16x8 bh = *(const bf16x8*)(Wh + n * KK2 + k0 + quad * 8);
                    const bf16x8 bl = *(const bf16x8*)(Wl + n * KK2 + k0 + quad * 8);
                    acc[nt] = __builtin_amdgcn_mfma_f32_16x16x32_bf16(ah, bh, acc[nt], 0, 0, 0);
                    acc[nt] = __builtin_amdgcn_mfma_f32_16x16x32_bf16(ah, bl, acc[nt], 0, 0, 0);
                    acc[nt] = __builtin_amdgcn_mfma_f32_16x16x32_bf16(al, bh, acc[nt], 0, 0, 0);
                }
            }
            #pragma unroll
            for (int nt = 0; nt < 4; ++nt) {
                const int n = wv * 64 + nt * 16 + l15;
                #pragma unroll
                for (int r = 0; r < 4; ++r) {
                    const int m = quad * 4 + r;
                    hb[m * HB_STRIDE + n] = fmaxf(acc[nt][r], 0.f);
                }
            }
        }
        __syncthreads();

        // ---- layer 3 (fp32, transposed W3, float4 k-loop) ----
        if (br == 0) {
            const int q = t >> 4, c = t & 15;
            float s = ob3[c];
            const float4* wv4 = (const float4*)(w3t + c * 256);
            const float4* hv4 = (const float4*)(hb + q * HB_STRIDE);
            for (int k4 = 0; k4 < 64; ++k4) {
                float4 h = hv4[k4], w = wv4[k4];
                s += h.x * w.x + h.y * w.y + h.z * w.z + h.w * w.w;
            }
            raw[q * 24 + c] = s;
        } else if (t < TQ * 8) {
            const int q = t >> 3, c = t & 7;
            float s = wb3[c];
            const float4* wv4 = (const float4*)(w3t + (16 + c) * 256);
            const float4* hv4 = (const float4*)(hb + q * HB_STRIDE);
            for (int k4 = 0; k4 < 64; ++k4) {
                float4 h = hv4[k4], w = wv4[k4];
                s += h.x * w.x + h.y * w.y + h.z * w.z + h.w * w.w;
            }
            raw[q * 24 + 16 + c] = s;
        }
        __syncthreads();
    }

    // ---- epilogue: tanh, softmax, bilinear indices+weights (alias dead xs) ----
    int*   sidx = (int*)xsh;         // [TQ][8][4]
    float* sw   = (float*)xsl;       // [TQ][8][4]
    if (t < TQ) {
        const int q = t;
        float m = -1e30f;
        #pragma unroll
        for (int p = 0; p < 8; ++p) m = fmaxf(m, raw[q * 24 + 16 + p]);
        float e[8]; float S = 0.f;
        #pragma unroll
        for (int p = 0; p < 8; ++p) { e[p] = expf(raw[q * 24 + 16 + p] - m); S += e[p]; }
        float s2 = 0.f;
        #pragma unroll
        for (int p = 0; p < 8; ++p) { e[p] /= S; s2 += e[p]; }
        const float inv = 1.f / fmaxf(s2, 1e-8f);

        const float px = pcs[q * 2 + 0], py = pcs[q * 2 + 1];
        #pragma unroll
        for (int p = 0; p < 8; ++p) {
            const float cx = px + 2.f * tanhf(raw[q * 24 + 2 * p]);
            const float cy = py + 2.f * tanhf(raw[q * 24 + 2 * p + 1]);
            const float gx = fminf(fmaxf(2.f * cx * (1.f / (WW - 1)) - 1.f, -1.1f), 1.1f);
            const float gy = fminf(fmaxf(2.f * cy * (1.f / (HH - 1)) - 1.f, -1.1f), 1.1f);
            const float ix = fminf(fmaxf((gx + 1.f) * 0.5f * (WW - 1), 0.f), (float)(WW - 1));
            const float iy = fminf(fmaxf((gy + 1.f) * 0.5f * (HH - 1), 0.f), (float)(HH - 1));
            const float x0 = floorf(ix), y0 = floorf(iy);
            const float wx = ix - x0, wy = iy - y0;
            const int x0i = (int)x0, y0i = (int)y0;
            const int x1i = min(x0i + 1, WW - 1), y1i = min(y0i + 1, HH - 1);
            const float nwp = e[p] * inv;
            const int b = (q * 8 + p) * 4;
            sidx[b + 0] = (y0i * WW + x0i) * (CC / 4);
            sidx[b + 1] = (y0i * WW + x1i) * (CC / 4);
            sidx[b + 2] = (y1i * WW + x0i) * (CC / 4);
            sidx[b + 3] = (y1i * WW + x1i) * (CC / 4);
            sw[b + 0] = (1.f - wx) * (1.f - wy) * nwp;
            sw[b + 1] = wx * (1.f - wy) * nwp;
            sw[b + 2] = (1.f - wx) * wy * nwp;
            sw[b + 3] = wx * wy * nwp;
        }
    }
    __syncthreads();

    // ---- gather + weighted sum ----
    const float4* fm4 = (const float4*)fmap;
    float4* out4 = (float4*)out;
    #pragma unroll
    for (int qq = 0; qq < 4; ++qq) {
        const int q = wv * 4 + qq;
        float4 acc; acc.x = acc.y = acc.z = acc.w = 0.f;
        for (int p = 0; p < 8; ++p) {
            const int b = (q * 8 + p) * 4;
            const int i00 = sidx[b + 0] + lane;
            const int i01 = sidx[b + 1] + lane;
            const int i10 = sidx[b + 2] + lane;
            const int i11 = sidx[b + 3] + lane;
            const float a00 = sw[b + 0], a01 = sw[b + 1], a10 = sw[b + 2], a11 = sw[b + 3];
            const float4 v00 = fm4[i00], v01 = fm4[i01], v10 = fm4[i10], v11 = fm4[i11];
            acc.x += a00 * v00.x + a01 * v01.x + a10 * v10.x + a11 * v11.x;
            acc.y += a00 * v00.y + a01 * v01.y + a10 * v10.y + a11 * v11.y;
            acc.z += a00 * v00.z + a01 * v01.z + a10 * v10.z + a11 * v11.z;
            acc.w += a00 * v00.w + a01 * v01.w + a10 * v10.w + a11 * v11.w;
        }
        out4[(size_t)(q0 + q) * (CC / 4) + lane] = acc;
    }
}

extern "C" void kernel_launch(void* const* d_in, const int* in_sizes, int n_in,
                              void* d_out, int out_size, void* d_ws, size_t ws_size,
                              hipStream_t stream) {
    const float* gq   = (const float*)d_in[0];
    const float* pc   = (const float*)d_in[1];
    const float* fmap = (const float*)d_in[2];
    const float* og   = (const float*)d_in[3];
    const float* obl  = (const float*)d_in[4];
    const float* oW1  = (const float*)d_in[5];
    const float* ob1  = (const float*)d_in[6];
    const float* oW2  = (const float*)d_in[7];
    const float* ob2  = (const float*)d_in[8];
    const float* oW3  = (const float*)d_in[9];
    const float* ob3  = (const float*)d_in[10];
    const float* wg   = (const float*)d_in[11];
    const float* wbl  = (const float*)d_in[12];
    const float* wW1  = (const float*)d_in[13];
    const float* wb1  = (const float*)d_in[14];
    const float* wW2  = (const float*)d_in[15];
    const float* wb2  = (const float*)d_in[16];
    const float* wW3  = (const float*)d_in[17];
    const float* wb3  = (const float*)d_in[18];

    char* ws = (char*)d_ws;
    unsigned short* w1th = (unsigned short*)(ws + WS_W1TH);
    unsigned short* w1tl = (unsigned short*)(ws + WS_W1TL);
    unsigned short* w2th = (unsigned short*)(ws + WS_W2TH);
    unsigned short* w2tl = (unsigned short*)(ws + WS_W2TL);
    float* w3t = (float*)(ws + WS_W3T);
    float* b1e = (float*)(ws + WS_B1E);
    float* out = (float*)d_out;

    prep_w1<<<dim3(KK1, 2), 256, 0, stream>>>(og, obl, oW1, ob1, wg, wbl, wW1, wb1, w1th, w1tl, b1e);
    prep_w2<<<dim3(KK2, 2), 256, 0, stream>>>(oW2, wW2, w2th, w2tl);
    prep_w3<<<2, 256, 0, stream>>>(oW3, wW3, w3t);
    fused_kernel<<<NQ / TQ, 256, 0, stream>>>(gq, pc, fmap, w1th, w1tl, w2th, w2tl, w3t, b1e,
                                              ob2, ob3, wb2, wb3, out);
}